// Round 3
// baseline (387.336 us; speedup 1.0000x reference)
//
#include <hip/hip_runtime.h>
#include <hip/hip_bf16.h>

// CrossAttention: B=4, C=256, H=W=64 -> N=M=4096, RC=32
// v3: - proj: weights read via wave-uniform global indices -> s_load + sgpr-FMA
//       (v2 read them from LDS: one ds_read per FMA = DS-pipe bound)
//     - attn: V staged to LDS via global_load_lds (async DMA), double-buffered,
//       1 barrier/iter; 2 q-tiles/wave (2x MFMA per V byte); K reg-prefetch.
//     - combine unchanged (HBM-bound).

#define B_ 4
#define C_ 256
#define N_ 4096
#define M_ 4096
#define RC_ 32
#define SCALE_ 0.17677669529663687f  // 1/sqrt(32)

typedef __bf16 bf16x8 __attribute__((ext_vector_type(8)));
typedef float f32x4 __attribute__((ext_vector_type(4)));

#define AS1 __attribute__((address_space(1)))
#define AS3 __attribute__((address_space(3)))

static __device__ __forceinline__ unsigned short f2bf(float f) {
    unsigned int u = __float_as_uint(f);
    unsigned int r = (u + 0x7fffu + ((u >> 16) & 1u)) >> 16;
    return (unsigned short)r;
}
static __device__ __forceinline__ float bf2f(unsigned int u) {
    return __uint_as_float(u << 16);
}
static __device__ __forceinline__ void gload_lds16(const void* g, void* l) {
    __builtin_amdgcn_global_load_lds((const AS1 unsigned int*)g,
                                     (AS3 unsigned int*)l, 16, 0, 0);
}

// ---------------------------------------------------------------------------
// Q/K projections. grid 128 x 256. Blocks 0..63: Q from x; 64..127: K from ctx.
// 1 pixel/thread, 32 outputs, c-loop over 256. Weights via uniform (scalar)
// loads; xv coalesced vector loads. Outputs pre-swizzled MFMA fragments.
// ---------------------------------------------------------------------------
__global__ __launch_bounds__(256) void proj_qk(
        const float* __restrict__ x, const float* __restrict__ ctx,
        const float* __restrict__ Wq, const float* __restrict__ bq,
        const float* __restrict__ Wk, const float* __restrict__ bk,
        unsigned short* __restrict__ Qf, unsigned short* __restrict__ Kf) {
    int bid = blockIdx.x;
    bool isK = bid >= 64;
    int lb = bid & 63;
    int b = lb >> 4;
    int p = ((lb & 15) << 8) + threadIdx.x;
    const float* __restrict__ W = isK ? Wk : Wq;
    const float* __restrict__ bias = isK ? bk : bq;
    const float* __restrict__ src = (isK ? ctx : x) + (size_t)b * C_ * N_ + p;

    float acc[RC_];
#pragma unroll
    for (int r = 0; r < RC_; r++) acc[r] = 0.f;
#pragma unroll 8
    for (int cc = 0; cc < C_; cc++) {
        float xv = src[(size_t)cc * N_];
#pragma unroll
        for (int r = 0; r < RC_; r++) acc[r] = fmaf(W[r * C_ + cc], xv, acc[r]);
    }
#pragma unroll
    for (int r = 0; r < RC_; r++) acc[r] += bias[r];

    size_t base;
    unsigned short* dst;
    if (!isK) {
        base = ((size_t)b * (N_ / 16) + (p >> 4)) * 64;
        dst = Qf;
    } else {
        base = (((size_t)b * (M_ / 32) + (p >> 5)) * 2 + ((p >> 4) & 1)) * 64;
        dst = Kf;
    }
#pragma unroll
    for (int q = 0; q < 4; q++) {
        uint4 pk;
        unsigned int w[4];
#pragma unroll
        for (int h = 0; h < 4; h++) {
            unsigned int lo = f2bf(acc[q * 8 + 2 * h]);
            unsigned int hi = f2bf(acc[q * 8 + 2 * h + 1]);
            w[h] = lo | (hi << 16);
        }
        pk.x = w[0]; pk.y = w[1]; pk.z = w[2]; pk.w = w[3];
        ((uint4*)dst)[base + (p & 15) + 16 * q] = pk;
    }
}

// ---------------------------------------------------------------------------
// V projection. grid (64, 8) x 256. 1 pixel/thread, 32 d-rows, c-loop 256.
// Weights scalar-loaded. Output in PV B-fragment order.
// ---------------------------------------------------------------------------
__global__ __launch_bounds__(256) void proj_v(
        const float* __restrict__ ctx, const float* __restrict__ Wv,
        const float* __restrict__ bv, unsigned short* __restrict__ Vf) {
    int b = blockIdx.x >> 4;
    int m = ((blockIdx.x & 15) << 8) + threadIdx.x;
    int d0 = blockIdx.y * 32;
    const float* __restrict__ W = Wv + (size_t)d0 * C_;
    const float* __restrict__ src = ctx + (size_t)b * C_ * M_ + m;

    float acc[32];
#pragma unroll
    for (int r = 0; r < 32; r++) acc[r] = 0.f;
#pragma unroll 8
    for (int cc = 0; cc < C_; cc++) {
        float xv = src[(size_t)cc * M_];
#pragma unroll
        for (int r = 0; r < 32; r++) acc[r] = fmaf(W[r * C_ + cc], xv, acc[r]);
    }

    int quad = (m >> 3) & 3, j = m & 7, mstep = m >> 5;
    size_t vb = ((size_t)b * (M_ / 32) + mstep) * 16;
#pragma unroll
    for (int r = 0; r < 32; r++) {
        int d = d0 + r;
        Vf[((vb + (d >> 4)) * 64 + (d & 15) + 16 * quad) * 8 + j] = f2bf(acc[r] + bv[d]);
    }
}

// ---------------------------------------------------------------------------
// Flash attention, split-m. grid 512 (2 blocks/CU), 256 thr (4 waves).
// blockIdx low4 = (b<<2)|chunk (XCD affinity), high 5 bits = ntg (0..31).
// Wave owns 2 q-tiles (32 rows). V double-buffered in LDS via global_load_lds;
// K prefetched to registers. Static-max softmax; partials to workspace.
// ---------------------------------------------------------------------------
__global__ __launch_bounds__(256, 2) void attn(
        const unsigned short* __restrict__ Qf, const unsigned short* __restrict__ Kf,
        const unsigned short* __restrict__ Vf, unsigned short* __restrict__ Op,
        float* __restrict__ Lp) {
    __shared__ __align__(16) uint4 vbuf[2][2048];            // 2 x 32 KB
    __shared__ __align__(16) unsigned short Plds[4][16][72]; // 9216 B

    int v = blockIdx.x & 15;
    int b = v >> 2, chunk = v & 3;
    int ntg = blockIdx.x >> 4;              // 0..31
    int wave = threadIdx.x >> 6, lane = threadIdx.x & 63;
    int quad = lane >> 4, col = lane & 15;
    int nt0 = ntg * 8 + wave * 2;           // tiles nt0, nt0+1

    const uint4* Qp = (const uint4*)Qf + (size_t)b * (N_ / 16) * 64;
    const uint4* Kp = (const uint4*)Kf + (size_t)b * (M_ / 32) * 2 * 64;
    const uint4* Vp = (const uint4*)Vf + (size_t)b * (M_ / 32) * 16 * 64;

    bf16x8 qa[2];
    qa[0] = __builtin_bit_cast(bf16x8, Qp[(size_t)(nt0 + 0) * 64 + lane]);
    qa[1] = __builtin_bit_cast(bf16x8, Qp[(size_t)(nt0 + 1) * 64 + lane]);

    f32x4 acc[2][16];
#pragma unroll
    for (int j = 0; j < 2; j++)
#pragma unroll
        for (int dt = 0; dt < 16; dt++) acc[j][dt] = (f32x4){0.f, 0.f, 0.f, 0.f};
    float lacc[2][4] = {{0.f, 0.f, 0.f, 0.f}, {0.f, 0.f, 0.f, 0.f}};

    unsigned short* Pw = &Plds[wave][0][0];
    const f32x4 zero = {0.f, 0.f, 0.f, 0.f};
    int ms0 = chunk * 16;

    // prologue: stage first V slab (32 chunks of 1KB; this wave takes 8)
#pragma unroll
    for (int i = 0; i < 8; i++) {
        int ck = wave * 8 + i;
        gload_lds16(Vp + ((size_t)(2 * ms0) * 16 + ck) * 64 + lane,
                    (char*)&vbuf[0][0] + ck * 1024 + lane * 16);
    }
    uint4 kv[4];
#pragma unroll
    for (int u = 0; u < 4; u++)
        kv[u] = Kp[((size_t)(2 * ms0 + (u >> 1)) * 2 + (u & 1)) * 64 + lane];

    int p = 0;
    for (int i = 0; i < 16; i++) {
        int ms = ms0 + i;
        __syncthreads();   // buf[p] staged & prior reads of buf[p^1] complete

        // stage next slab into the other buffer (in flight during compute)
        int msn = (i < 15) ? ms + 1 : ms;
#pragma unroll
        for (int ii = 0; ii < 8; ii++) {
            int ck = wave * 8 + ii;
            gload_lds16(Vp + ((size_t)(2 * msn) * 16 + ck) * 64 + lane,
                        (char*)&vbuf[p ^ 1][0] + ck * 1024 + lane * 16);
        }
        uint4 kvn[4];
#pragma unroll
        for (int u = 0; u < 4; u++)
            kvn[u] = Kp[((size_t)(2 * msn + (u >> 1)) * 2 + (u & 1)) * 64 + lane];

        // S = Q K^T, softmax, P via wave-private LDS (sequential for 2 tiles)
        bf16x8 pa[2][2];
#pragma unroll
        for (int j = 0; j < 2; j++) {
            f32x4 s[4];
#pragma unroll
            for (int u = 0; u < 4; u++)
                s[u] = __builtin_amdgcn_mfma_f32_16x16x32_bf16(
                    qa[j], __builtin_bit_cast(bf16x8, kv[u]), zero, 0, 0, 0);
#pragma unroll
            for (int u = 0; u < 4; u++) {
#pragma unroll
                for (int r = 0; r < 4; r++) {
                    float pe = __expf(s[u][r] * SCALE_);
                    lacc[j][r] += pe;
                    Pw[(quad * 4 + r) * 72 + u * 16 + col] = f2bf(pe);
                }
            }
            pa[j][0] = *(const bf16x8*)(&Pw[col * 72 + quad * 8]);
            pa[j][1] = *(const bf16x8*)(&Pw[col * 72 + 32 + quad * 8]);
        }

        // O += P V'  (V fragments from LDS)
        const uint4* vb = &vbuf[p][0];
#pragma unroll
        for (int dt = 0; dt < 16; dt++) {
            uint4 v0 = vb[dt * 64 + lane];
            uint4 v1 = vb[(16 + dt) * 64 + lane];
            acc[0][dt] = __builtin_amdgcn_mfma_f32_16x16x32_bf16(
                pa[0][0], __builtin_bit_cast(bf16x8, v0), acc[0][dt], 0, 0, 0);
            acc[0][dt] = __builtin_amdgcn_mfma_f32_16x16x32_bf16(
                pa[0][1], __builtin_bit_cast(bf16x8, v1), acc[0][dt], 0, 0, 0);
            acc[1][dt] = __builtin_amdgcn_mfma_f32_16x16x32_bf16(
                pa[1][0], __builtin_bit_cast(bf16x8, v0), acc[1][dt], 0, 0, 0);
            acc[1][dt] = __builtin_amdgcn_mfma_f32_16x16x32_bf16(
                pa[1][1], __builtin_bit_cast(bf16x8, v1), acc[1][dt], 0, 0, 0);
        }
#pragma unroll
        for (int u = 0; u < 4; u++) kv[u] = kvn[u];
        p ^= 1;
    }

    // l reduction over the 16 cols of each quad-row
#pragma unroll
    for (int off = 1; off <= 8; off <<= 1) {
#pragma unroll
        for (int j = 0; j < 2; j++)
#pragma unroll
            for (int r = 0; r < 4; r++)
                lacc[j][r] += __shfl_xor(lacc[j][r], off, 64);
    }
#pragma unroll
    for (int j = 0; j < 2; j++) {
        int tileg = b * 256 + nt0 + j;
        if (col == 0) {
#pragma unroll
            for (int r = 0; r < 4; r++)
                Lp[((size_t)tileg * 4 + chunk) * 16 + quad * 4 + r] = lacc[j][r];
        }
#pragma unroll
        for (int dt = 0; dt < 16; dt++) {
            int d = dt * 16 + col;
            size_t sb = ((size_t)(b * 4 + chunk) * C_ + d) * N_ + (nt0 + j) * 16 + quad * 4;
            uint2 pk;
            pk.x = (unsigned)f2bf(acc[j][dt][0]) | ((unsigned)f2bf(acc[j][dt][1]) << 16);
            pk.y = (unsigned)f2bf(acc[j][dt][2]) | ((unsigned)f2bf(acc[j][dt][3]) << 16);
            *(uint2*)(Op + sb) = pk;
        }
    }
}

// ---------------------------------------------------------------------------
// Combine: out = gamma * (sum_c O_c) / (sum_c l_c) + x. Coalesced, HBM-bound.
// ---------------------------------------------------------------------------
__global__ __launch_bounds__(256) void combine(
        const unsigned short* __restrict__ Op, const float* __restrict__ Lp,
        const float* __restrict__ x, const float* __restrict__ gamma,
        float* __restrict__ out) {
    int idx = blockIdx.x * 256 + threadIdx.x;
    int n4 = idx & 1023;
    int d = (idx >> 10) & 255;
    int b = idx >> 18;
    int n = n4 * 4;
    int tile = b * 256 + (n >> 4);
    int row0 = n & 15;

    float o[4] = {0.f, 0.f, 0.f, 0.f};
    float l[4] = {0.f, 0.f, 0.f, 0.f};
#pragma unroll
    for (int c = 0; c < 4; c++) {
        size_t sb = ((size_t)(b * 4 + c) * C_ + d) * N_ + n;
        uint2 pv = *(const uint2*)(Op + sb);
        o[0] += bf2f(pv.x & 0xffffu);
        o[1] += bf2f(pv.x >> 16);
        o[2] += bf2f(pv.y & 0xffffu);
        o[3] += bf2f(pv.y >> 16);
        const float* lp = &Lp[((size_t)tile * 4 + c) * 16 + row0];
#pragma unroll
        for (int r = 0; r < 4; r++) l[r] += lp[r];
    }
    float g = gamma[0];
    size_t ob = ((size_t)b * C_ + d) * N_ + n;
    f32x4 xv = *(const f32x4*)(x + ob);
    f32x4 res;
#pragma unroll
    for (int r = 0; r < 4; r++) res[r] = g * o[r] / l[r] + xv[r];
    *(f32x4*)(out + ob) = res;
}

// ---------------------------------------------------------------------------
extern "C" void kernel_launch(void* const* d_in, const int* in_sizes, int n_in,
                              void* d_out, int out_size, void* d_ws, size_t ws_size,
                              hipStream_t stream) {
    const float* x     = (const float*)d_in[0];
    const float* ctx   = (const float*)d_in[1];
    const float* Wq    = (const float*)d_in[2];
    const float* bq    = (const float*)d_in[3];
    const float* Wk    = (const float*)d_in[4];
    const float* bk    = (const float*)d_in[5];
    const float* Wv    = (const float*)d_in[6];
    const float* bv    = (const float*)d_in[7];
    const float* gamma = (const float*)d_in[8];
    float* out = (float*)d_out;

    // ws: Qf 1MB | Kf 1MB | Vf 8.4MB | Op 33.6MB | Lp 256KB
    unsigned short* Qf = (unsigned short*)d_ws;
    unsigned short* Kf = Qf + (size_t)B_ * N_ * RC_;
    unsigned short* Vf = Kf + (size_t)B_ * M_ * RC_;
    unsigned short* Op = Vf + (size_t)B_ * M_ * C_;
    float* Lp = (float*)(Op + (size_t)B_ * 4 * C_ * N_);

    proj_qk<<<128, 256, 0, stream>>>(x, ctx, Wq, bq, Wk, bk, Qf, Kf);
    proj_v<<<dim3(64, 8), 256, 0, stream>>>(ctx, Wv, bv, Vf);
    attn<<<512, 256, 0, stream>>>(Qf, Kf, Vf, Op, Lp);
    combine<<<4096, 256, 0, stream>>>(Op, Lp, x, gamma, out);
}

// Round 4
// 177.311 us; speedup vs baseline: 2.1845x; 2.1845x over previous
//
#include <hip/hip_runtime.h>
#include <hip/hip_bf16.h>

// CrossAttention: B=4, C=256, H=W=64 -> N=M=4096, RC=32
// v4: transpose x/ctx to bf16 pixel-major; MFMA-based projections emitting
//     attn-ready swizzled fragments; attn with fp8 P/V (fp8_fp8 MFMA) and
//     fp8 partial-O; combine decodes fp8 and fuses residual.

#define B_ 4
#define C_ 256
#define N_ 4096
#define M_ 4096
#define SCALE_ 0.17677669529663687f  // 1/sqrt(32)

typedef __bf16 bf16x8 __attribute__((ext_vector_type(8)));
typedef float f32x4 __attribute__((ext_vector_type(4)));

#define AS1 __attribute__((address_space(1)))
#define AS3 __attribute__((address_space(3)))

static __device__ __forceinline__ unsigned short f2bf(float f) {
    unsigned int u = __float_as_uint(f);
    return (unsigned short)((u + 0x7fffu + ((u >> 16) & 1u)) >> 16);
}
static __device__ __forceinline__ unsigned bfpk(float a, float b) {
    return (unsigned)f2bf(a) | ((unsigned)f2bf(b) << 16);
}
static __device__ __forceinline__ float fp8d(unsigned v) {  // e4m3fn decode
    unsigned e = (v >> 3) & 15, m = v & 7;
    float f = e ? __uint_as_float(((e + 120u) << 23) | (m << 20))
                : (float)m * 0x1p-9f;
    return (v & 0x80u) ? -f : f;
}
static __device__ __forceinline__ void gload_lds16(const void* g, void* l) {
    __builtin_amdgcn_global_load_lds((const AS1 unsigned int*)g,
                                     (AS3 unsigned int*)l, 16, 0, 0);
}

// ---------------------------------------------------------------------------
// Transpose: in[b][c][p] fp32 -> out[b][p][c] bf16.  grid 2048 x 256.
// bid: tens(1) | b(2) | ptile(6) | ctile(2).  64x64 tiles via LDS.
// ---------------------------------------------------------------------------
__global__ __launch_bounds__(256) void transpose_bf(
        const float* __restrict__ x, const float* __restrict__ ctx,
        unsigned short* __restrict__ xT, unsigned short* __restrict__ ctxT) {
    __shared__ unsigned short T[64][68];  // pad 4 -> 2-way banks on write
    int bid = blockIdx.x;
    int tens = bid >> 10;
    int r = bid & 1023;
    int b = r >> 8, rr = r & 255;
    int pt = rr >> 2, ct = rr & 3;
    const float* __restrict__ in = (tens ? ctx : x) + (size_t)b * C_ * N_;
    unsigned short* __restrict__ outp = (tens ? ctxT : xT) + (size_t)b * N_ * C_;
    int t = threadIdx.x;

    {   // read 64c x 64p, write LDS transposed (bf16)
        int p = t & 63, cg = t >> 6;  // cg*16 c-rows per thread
        const float* src = in + (size_t)(ct * 64 + cg * 16) * N_ + pt * 64 + p;
        float v[16];
#pragma unroll
        for (int k = 0; k < 16; k++) v[k] = src[(size_t)k * N_];
#pragma unroll
        for (int k = 0; k < 16; k += 2)
            *(unsigned*)&T[p][cg * 16 + k] = bfpk(v[k], v[k + 1]);
    }
    __syncthreads();
    {   // read LDS rows, store coalesced to out[p][c]
        int p2 = t >> 2, cq = t & 3;
        uint2 a = *(const uint2*)&T[p2][cq * 16];
        uint2 bq_ = *(const uint2*)&T[p2][cq * 16 + 4];
        uint2 c = *(const uint2*)&T[p2][cq * 16 + 8];
        uint2 d = *(const uint2*)&T[p2][cq * 16 + 12];
        size_t ob = (size_t)(pt * 64 + p2) * C_ + ct * 64 + cq * 16;
        uint4 s0 = {a.x, a.y, bq_.x, bq_.y};
        uint4 s1 = {c.x, c.y, d.x, d.y};
        *(uint4*)(outp + ob) = s0;
        *(uint4*)(outp + ob + 8) = s1;
    }
}

// ---------------------------------------------------------------------------
// Q/K projection GEMM. grid 256 x 256 thr. bid>>7: 0=Q(from xT),1=K(from ctxT).
// Wave: all 32 rc x 2 ptiles. W-fragments hoisted to VGPRs; input frags are
// direct dwordx4 from the bf16 transposed tensor. Epilogue re-swizzles via
// wave-private LDS into attn fragment order (uint4 per lane per ptile).
// ---------------------------------------------------------------------------
__global__ __launch_bounds__(256) void proj_qk(
        const unsigned short* __restrict__ xT, const unsigned short* __restrict__ ctxT,
        const float* __restrict__ Wq, const float* __restrict__ bq,
        const float* __restrict__ Wk, const float* __restrict__ bk,
        unsigned short* __restrict__ Qf, unsigned short* __restrict__ Kf) {
    __shared__ unsigned short Pl[4][16 * 40];  // per-wave, stride 40 (80B, 16-al)
    int bid = blockIdx.x;
    int tens = bid >> 7;
    int blk = bid & 127;
    int wave = threadIdx.x >> 6, lane = threadIdx.x & 63;
    int q = lane >> 4, low = lane & 15;
    const unsigned short* __restrict__ in = tens ? ctxT : xT;
    const float* __restrict__ W = tens ? Wk : Wq;
    const float* __restrict__ bias = tens ? bk : bq;
    unsigned short* __restrict__ dst = tens ? Kf : Qf;

    // hoist W fragments: af[rt][ch], lane holds W[rt*16+low][ch*32+q*8 ..+7]
    bf16x8 af[2][8];
#pragma unroll
    for (int rt = 0; rt < 2; rt++)
#pragma unroll
        for (int ch = 0; ch < 8; ch++) {
            const float* wp = W + (size_t)(rt * 16 + low) * C_ + ch * 32 + q * 8;
            float4 w0 = *(const float4*)wp;
            float4 w1 = *(const float4*)(wp + 4);
            uint4 pk = {bfpk(w0.x, w0.y), bfpk(w0.z, w0.w),
                        bfpk(w1.x, w1.y), bfpk(w1.z, w1.w)};
            af[rt][ch] = __builtin_bit_cast(bf16x8, pk);
        }
    float bb[2][4];
#pragma unroll
    for (int rt = 0; rt < 2; rt++)
#pragma unroll
        for (int rg = 0; rg < 4; rg++) bb[rt][rg] = bias[rt * 16 + q * 4 + rg];

    unsigned short* Pw = &Pl[wave][0];
    const f32x4 zero = {0.f, 0.f, 0.f, 0.f};

    for (int i = 0; i < 2; i++) {
        int pt = blk * 8 + wave * 2 + i;      // 0..1023
        int b = pt >> 8, ptl = pt & 255;
        const unsigned short* src = in + ((size_t)b * N_ + ptl * 16 + low) * C_;
        f32x4 acc[2] = {zero, zero};
#pragma unroll
        for (int ch = 0; ch < 8; ch++) {
            uint4 bv = *(const uint4*)(src + ch * 32 + q * 8);
            bf16x8 bfr = __builtin_bit_cast(bf16x8, bv);
            acc[0] = __builtin_amdgcn_mfma_f32_16x16x32_bf16(af[0][ch], bfr, acc[0], 0, 0, 0);
            acc[1] = __builtin_amdgcn_mfma_f32_16x16x32_bf16(af[1][ch], bfr, acc[1], 0, 0, 0);
        }
        // D: row = rc = q*4+reg (per rt), col = p = low. Write LDS [p][rc].
#pragma unroll
        for (int rt = 0; rt < 2; rt++) {
            uint2 pk = {bfpk(acc[rt][0] + bb[rt][0], acc[rt][1] + bb[rt][1]),
                        bfpk(acc[rt][2] + bb[rt][2], acc[rt][3] + bb[rt][3])};
            *(uint2*)(Pw + low * 40 + rt * 16 + q * 4) = pk;
        }
        // read attn A/B-frag: lane(low=p, q) gets rc q*8..q*8+7
        uint4 frag = *(const uint4*)(Pw + low * 40 + q * 8);
        ((uint4*)dst)[(size_t)(b * 256 + ptl) * 64 + lane] = frag;
    }
}

// ---------------------------------------------------------------------------
// V projection GEMM. grid 512 x 256 thr. bid: mg(6)|dg(3). Wave: 32 d x 2 mc
// (mc = 32-m chunk). Wv fragments hoisted; ctxT frags direct dwordx4.
// Epilogue: bias + fp8 pack + wave-private LDS re-swizzle -> Vf in attn
// B-fragment order: uint2 per lane per (mc, dtile).
// ---------------------------------------------------------------------------
__global__ __launch_bounds__(256) void proj_v(
        const unsigned short* __restrict__ ctxT, const float* __restrict__ Wv,
        const float* __restrict__ bv, unsigned char* __restrict__ Vf) {
    __shared__ unsigned char Vl[4][32 * 40];  // per-wave [32 d][32 m +8]
    int bid = blockIdx.x;
    int dg = bid & 7;           // d-group: d0 = dg*32
    int mg = bid >> 3;          // 0..63
    int wave = threadIdx.x >> 6, lane = threadIdx.x & 63;
    int q = lane >> 4, low = lane & 15;

    bf16x8 bf[2][8];            // Wv frags: lane holds Wv[dg*32+dt*16+low][ch*32+q*8..]
#pragma unroll
    for (int dt = 0; dt < 2; dt++)
#pragma unroll
        for (int ch = 0; ch < 8; ch++) {
            const float* wp = Wv + (size_t)(dg * 32 + dt * 16 + low) * C_ + ch * 32 + q * 8;
            float4 w0 = *(const float4*)wp;
            float4 w1 = *(const float4*)(wp + 4);
            uint4 pk = {bfpk(w0.x, w0.y), bfpk(w0.z, w0.w),
                        bfpk(w1.x, w1.y), bfpk(w1.z, w1.w)};
            bf[dt][ch] = __builtin_bit_cast(bf16x8, pk);
        }
    float bvv[2];
    bvv[0] = bv[dg * 32 + low];
    bvv[1] = bv[dg * 32 + 16 + low];

    unsigned char* Vw = &Vl[wave][0];
    const f32x4 zero = {0.f, 0.f, 0.f, 0.f};

    for (int i = 0; i < 2; i++) {
        int mc = mg * 8 + wave * 2 + i;       // 0..511
        int b = mc >> 7, mcl = mc & 127;
        f32x4 acc[2][2];                       // [mt][dt]
#pragma unroll
        for (int mt = 0; mt < 2; mt++) {
            acc[mt][0] = zero; acc[mt][1] = zero;
            const unsigned short* src =
                ctxT + ((size_t)b * M_ + mcl * 32 + mt * 16 + low) * C_;
#pragma unroll
            for (int ch = 0; ch < 8; ch++) {
                uint4 av = *(const uint4*)(src + ch * 32 + q * 8);
                bf16x8 afr = __builtin_bit_cast(bf16x8, av);
                acc[mt][0] = __builtin_amdgcn_mfma_f32_16x16x32_bf16(afr, bf[0][ch], acc[mt][0], 0, 0, 0);
                acc[mt][1] = __builtin_amdgcn_mfma_f32_16x16x32_bf16(afr, bf[1][ch], acc[mt][1], 0, 0, 0);
            }
        }
        // D: row = m = q*4+reg (within mt), col = d = low. LDS [d][m] fp8.
#pragma unroll
        for (int mt = 0; mt < 2; mt++)
#pragma unroll
            for (int dt = 0; dt < 2; dt++) {
                float v0 = acc[mt][dt][0] + bvv[dt], v1 = acc[mt][dt][1] + bvv[dt];
                float v2 = acc[mt][dt][2] + bvv[dt], v3 = acc[mt][dt][3] + bvv[dt];
                unsigned w = __builtin_amdgcn_cvt_pk_fp8_f32(v0, v1, 0, false);
                w = __builtin_amdgcn_cvt_pk_fp8_f32(v2, v3, w, true);
                *(unsigned*)(Vw + (dt * 16 + low) * 40 + mt * 16 + q * 4) = w;
            }
        // read Vf frag: lane(low=d, q) gets m q*8..+7; store per dtile
#pragma unroll
        for (int dt = 0; dt < 2; dt++) {
            uint2 frag = *(const uint2*)(Vw + (dt * 16 + low) * 40 + q * 8);
            ((uint2*)Vf)[(((size_t)b * 128 + mcl) * 16 + dg * 2 + dt) * 64 + lane] = frag;
        }
    }
}

// ---------------------------------------------------------------------------
// Flash attention, split-m. grid 512, 256 thr (4 waves), 2 blocks/CU.
// fp8 P and V; PV via mfma fp8_fp8. V double-buffered in LDS (16 KB slabs)
// via global_load_lds. Partial O in fp8, l in fp32.
// ---------------------------------------------------------------------------
__global__ __launch_bounds__(256, 2) void attn(
        const unsigned short* __restrict__ Qf, const unsigned short* __restrict__ Kf,
        const unsigned char* __restrict__ Vf, unsigned char* __restrict__ Op,
        float* __restrict__ Lp) {
    __shared__ __align__(16) unsigned char vbuf[2][16384];
    __shared__ __align__(16) unsigned char Plds[4][16 * 72];

    int v = blockIdx.x & 15;
    int b = v >> 2, chunk = v & 3;
    int ntg = blockIdx.x >> 4;              // 0..31
    int wave = threadIdx.x >> 6, lane = threadIdx.x & 63;
    int quad = lane >> 4, col = lane & 15;
    int nt0 = ntg * 8 + wave * 2;

    const uint4* Qp = (const uint4*)Qf;
    const uint4* Kp = (const uint4*)Kf + (size_t)b * 256 * 64;
    const unsigned char* Vp = Vf + (size_t)b * 1048576;

    bf16x8 qa[2];
    qa[0] = __builtin_bit_cast(bf16x8, Qp[(size_t)(b * 256 + nt0 + 0) * 64 + lane]);
    qa[1] = __builtin_bit_cast(bf16x8, Qp[(size_t)(b * 256 + nt0 + 1) * 64 + lane]);

    f32x4 acc[2][16];
#pragma unroll
    for (int j = 0; j < 2; j++)
#pragma unroll
        for (int dt = 0; dt < 16; dt++) acc[j][dt] = (f32x4){0.f, 0.f, 0.f, 0.f};
    float lacc[2][4] = {{0.f, 0.f, 0.f, 0.f}, {0.f, 0.f, 0.f, 0.f}};

    unsigned char* Pw = &Plds[wave][0];
    const f32x4 zero = {0.f, 0.f, 0.f, 0.f};
    int ms0 = chunk * 16;

    // prologue: stage first 16 KB V slab (16 chunks of 1 KB; 4 per wave)
#pragma unroll
    for (int ii = 0; ii < 4; ii++) {
        int ck = wave * 4 + ii;
        gload_lds16(Vp + (size_t)ms0 * 16384 + ck * 1024 + lane * 16,
                    &vbuf[0][0] + ck * 1024 + lane * 16);
    }
    uint4 kv[4];
#pragma unroll
    for (int u = 0; u < 4; u++)
        kv[u] = Kp[(size_t)(ms0 * 4 + u) * 64 + lane];

    int p = 0;
    for (int i = 0; i < 16; i++) {
        int ms = ms0 + i;
        __syncthreads();

        int msn = (i < 15) ? ms + 1 : ms;
#pragma unroll
        for (int ii = 0; ii < 4; ii++) {
            int ck = wave * 4 + ii;
            gload_lds16(Vp + (size_t)msn * 16384 + ck * 1024 + lane * 16,
                        &vbuf[p ^ 1][0] + ck * 1024 + lane * 16);
        }
        uint4 kvn[4];
#pragma unroll
        for (int u = 0; u < 4; u++)
            kvn[u] = Kp[(size_t)(msn * 4 + u) * 64 + lane];

        unsigned long long pa[2][2];
#pragma unroll
        for (int j = 0; j < 2; j++) {
            f32x4 s[4];
#pragma unroll
            for (int u = 0; u < 4; u++)
                s[u] = __builtin_amdgcn_mfma_f32_16x16x32_bf16(
                    qa[j], __builtin_bit_cast(bf16x8, kv[u]), zero, 0, 0, 0);
#pragma unroll
            for (int u = 0; u < 4; u++) {
#pragma unroll
                for (int r = 0; r < 4; r++) {
                    float pe = __expf(s[u][r] * SCALE_);
                    lacc[j][r] += pe;
                    unsigned w8 = __builtin_amdgcn_cvt_pk_fp8_f32(pe, pe, 0, false);
                    Pw[(quad * 4 + r) * 72 + u * 16 + col] = (unsigned char)w8;
                }
            }
            pa[j][0] = *(const unsigned long long*)(Pw + col * 72 + quad * 8);
            pa[j][1] = *(const unsigned long long*)(Pw + col * 72 + 32 + quad * 8);
        }

        const unsigned char* vb = &vbuf[p][0];
#pragma unroll
        for (int dt = 0; dt < 16; dt++) {
            long v0 = *(const long*)(vb + (size_t)dt * 512 + lane * 8);
            long v1 = *(const long*)(vb + (size_t)(16 + dt) * 512 + lane * 8);
            acc[0][dt] = __builtin_amdgcn_mfma_f32_16x16x32_fp8_fp8(
                (long)pa[0][0], v0, acc[0][dt], 0, 0, 0);
            acc[0][dt] = __builtin_amdgcn_mfma_f32_16x16x32_fp8_fp8(
                (long)pa[0][1], v1, acc[0][dt], 0, 0, 0);
            acc[1][dt] = __builtin_amdgcn_mfma_f32_16x16x32_fp8_fp8(
                (long)pa[1][0], v0, acc[1][dt], 0, 0, 0);
            acc[1][dt] = __builtin_amdgcn_mfma_f32_16x16x32_fp8_fp8(
                (long)pa[1][1], v1, acc[1][dt], 0, 0, 0);
        }
#pragma unroll
        for (int u = 0; u < 4; u++) kv[u] = kvn[u];
        p ^= 1;
    }

#pragma unroll
    for (int off = 1; off <= 8; off <<= 1) {
#pragma unroll
        for (int j = 0; j < 2; j++)
#pragma unroll
            for (int r = 0; r < 4; r++)
                lacc[j][r] += __shfl_xor(lacc[j][r], off, 64);
    }
#pragma unroll
    for (int j = 0; j < 2; j++) {
        int tileg = b * 256 + nt0 + j;
        if (col == 0) {
#pragma unroll
            for (int r = 0; r < 4; r++)
                Lp[((size_t)tileg * 4 + chunk) * 16 + quad * 4 + r] = lacc[j][r];
        }
#pragma unroll
        for (int dt = 0; dt < 16; dt++) {
            int d = dt * 16 + col;
            size_t sb = ((size_t)(b * 4 + chunk) * C_ + d) * N_ + (nt0 + j) * 16 + quad * 4;
            unsigned w = __builtin_amdgcn_cvt_pk_fp8_f32(acc[j][dt][0], acc[j][dt][1], 0, false);
            w = __builtin_amdgcn_cvt_pk_fp8_f32(acc[j][dt][2], acc[j][dt][3], w, true);
            *(unsigned*)(Op + sb) = w;
        }
    }
}

// ---------------------------------------------------------------------------
// Combine: out = gamma * (sum_c O_c) / (sum_c l_c) + x. HBM-bound.
// ---------------------------------------------------------------------------
__global__ __launch_bounds__(256) void combine(
        const unsigned char* __restrict__ Op, const float* __restrict__ Lp,
        const float* __restrict__ x, const float* __restrict__ gamma,
        float* __restrict__ out) {
    int idx = blockIdx.x * 256 + threadIdx.x;
    int n4 = idx & 1023;
    int d = (idx >> 10) & 255;
    int b = idx >> 18;
    int n = n4 * 4;
    int tile = b * 256 + (n >> 4);
    int row0 = n & 15;

    float o[4] = {0.f, 0.f, 0.f, 0.f};
    float l[4] = {0.f, 0.f, 0.f, 0.f};
#pragma unroll
    for (int c = 0; c < 4; c++) {
        size_t sb = ((size_t)(b * 4 + c) * C_ + d) * N_ + n;
        unsigned pv = *(const unsigned*)(Op + sb);
        o[0] += fp8d(pv & 0xffu);
        o[1] += fp8d((pv >> 8) & 0xffu);
        o[2] += fp8d((pv >> 16) & 0xffu);
        o[3] += fp8d(pv >> 24);
        const float* lp = &Lp[((size_t)tile * 4 + c) * 16 + row0];
#pragma unroll
        for (int r = 0; r < 4; r++) l[r] += lp[r];
    }
    float g = gamma[0];
    size_t ob = ((size_t)b * C_ + d) * N_ + n;
    f32x4 xv = *(const f32x4*)(x + ob);
    f32x4 res;
#pragma unroll
    for (int r = 0; r < 4; r++) res[r] = g * o[r] / l[r] + xv[r];
    *(f32x4*)(out + ob) = res;
}

// ---------------------------------------------------------------------------
extern "C" void kernel_launch(void* const* d_in, const int* in_sizes, int n_in,
                              void* d_out, int out_size, void* d_ws, size_t ws_size,
                              hipStream_t stream) {
    const float* x     = (const float*)d_in[0];
    const float* ctx   = (const float*)d_in[1];
    const float* Wq    = (const float*)d_in[2];
    const float* bq    = (const float*)d_in[3];
    const float* Wk    = (const float*)d_in[4];
    const float* bk    = (const float*)d_in[5];
    const float* Wv    = (const float*)d_in[6];
    const float* bv    = (const float*)d_in[7];
    const float* gamma = (const float*)d_in[8];
    float* out = (float*)d_out;

    // ws: xT 8.4M | ctxT 8.4M | Qf 1M | Kf 1M | Vf 4.2M | Op 8.4M | Lp 1M  (~33MB)
    unsigned short* xT   = (unsigned short*)d_ws;
    unsigned short* ctxT = xT + (size_t)B_ * N_ * C_;
    unsigned short* Qf   = ctxT + (size_t)B_ * M_ * C_;
    unsigned short* Kf   = Qf + (size_t)B_ * N_ * 32;
    unsigned char*  Vf   = (unsigned char*)(Kf + (size_t)B_ * M_ * 32);
    unsigned char*  Op   = Vf + (size_t)B_ * M_ * C_;
    float*          Lp   = (float*)(Op + (size_t)B_ * 4 * C_ * N_);

    transpose_bf<<<2048, 256, 0, stream>>>(x, ctx, xT, ctxT);
    proj_qk<<<256, 256, 0, stream>>>(xT, ctxT, Wq, bq, Wk, bk, Qf, Kf);
    proj_v<<<512, 256, 0, stream>>>(ctxT, Wv, bv, Vf);
    attn<<<512, 256, 0, stream>>>(Qf, Kf, Vf, Op, Lp);
    combine<<<4096, 256, 0, stream>>>(Op, Lp, x, gamma, out);
}